// Round 1
// baseline (719.268 us; speedup 1.0000x reference)
//
#include <hip/hip_runtime.h>

#define TB 4
#define TT 2048
#define TC 2048
#define NH 16
#define NKV 4
#define HD 128
#define KVDIM (NKV*HD)        // 512
#define NQKV (TC + 2*KVDIM)   // 3072
#define MTOK (TB*TT)          // 8192

typedef __bf16 bf16x8 __attribute__((ext_vector_type(8)));
typedef __bf16 bf16x4 __attribute__((ext_vector_type(4)));
typedef float  f32x4  __attribute__((ext_vector_type(4)));
typedef unsigned short ushort_t;
typedef unsigned short us8 __attribute__((ext_vector_type(8)));
typedef unsigned short us4 __attribute__((ext_vector_type(4)));

__device__ __forceinline__ ushort_t f2bf(float f) {
    unsigned u = __builtin_bit_cast(unsigned, f);
    u += 0x7fffu + ((u >> 16) & 1u);
    return (ushort_t)(u >> 16);
}

// ---------------- cast f32 -> bf16 (vectorized, grid-stride) ----------------
__global__ __launch_bounds__(256) void cast_bf16(const float* __restrict__ in,
                                                 ushort_t* __restrict__ out, long n) {
    long i = (long)blockIdx.x * blockDim.x + threadIdx.x;
    long stride = (long)gridDim.x * blockDim.x;
    for (long e = i * 4; e < n; e += stride * 4) {
        float4 v = *reinterpret_cast<const float4*>(in + e);
        us4 o;
        o[0] = f2bf(v.x); o[1] = f2bf(v.y); o[2] = f2bf(v.z); o[3] = f2bf(v.w);
        *reinterpret_cast<us4*>(out + e) = o;
    }
}

// ---------------- GEMM: C[M][N] = A[M][K](bf16) * Bw[N][K](bf16)^T -----------
// 128x128 tile, BK=32, 256 threads = 4 waves (2x2), 16x16x32 MFMA.
#define GBM 128
#define GBN 128
#define GBK 32

template<bool OUTF32>
__global__ __launch_bounds__(256) void gemm_bt(const ushort_t* __restrict__ A,
                                               const ushort_t* __restrict__ Bw,
                                               float* __restrict__ Cf,
                                               ushort_t* __restrict__ Cb,
                                               int M, int N, int K) {
    __shared__ alignas(16) ushort_t As[GBM * GBK];
    __shared__ alignas(16) ushort_t Bs[GBN * GBK];

    const int tid = threadIdx.x;
    const int bm = blockIdx.y, bn = blockIdx.x;
    const int lane = tid & 63, wid = tid >> 6;
    const int wm = wid >> 1, wn = wid & 1;
    const int g = lane >> 4, l16 = lane & 15;

    f32x4 acc[4][4] = {};

    const int srow = tid >> 1;          // 0..127
    const int scol = (tid & 1) * 16;    // 0 or 16
    const ushort_t* Ag = A  + (size_t)(bm * GBM + srow) * K + scol;
    const ushort_t* Bg = Bw + (size_t)(bn * GBN + srow) * K + scol;
    const int wix  = srow * GBK + scol;
    const int sw   = (srow & 3) << 3;          // XOR-swizzle (16B granules)
    const int wsw0 = wix ^ sw;
    const int wsw1 = (wix + 8) ^ sw;

    for (int kt = 0; kt < K; kt += GBK) {
        us8 a0 = *reinterpret_cast<const us8*>(Ag + kt);
        us8 a1 = *reinterpret_cast<const us8*>(Ag + kt + 8);
        us8 b0 = *reinterpret_cast<const us8*>(Bg + kt);
        us8 b1 = *reinterpret_cast<const us8*>(Bg + kt + 8);
        __syncthreads();                 // previous iteration's reads done
        *reinterpret_cast<us8*>(&As[wsw0]) = a0;
        *reinterpret_cast<us8*>(&As[wsw1]) = a1;
        *reinterpret_cast<us8*>(&Bs[wsw0]) = b0;
        *reinterpret_cast<us8*>(&Bs[wsw1]) = b1;
        __syncthreads();

        bf16x8 af[4], bfr[4];
#pragma unroll
        for (int mi = 0; mi < 4; mi++) {
            int row = wm * 64 + mi * 16 + l16;
            int ix = (row * GBK + g * 8) ^ ((row & 3) << 3);
            af[mi] = *reinterpret_cast<const bf16x8*>(&As[ix]);
        }
#pragma unroll
        for (int nj = 0; nj < 4; nj++) {
            int row = wn * 64 + nj * 16 + l16;
            int ix = (row * GBK + g * 8) ^ ((row & 3) << 3);
            bfr[nj] = *reinterpret_cast<const bf16x8*>(&Bs[ix]);
        }
#pragma unroll
        for (int mi = 0; mi < 4; mi++)
#pragma unroll
            for (int nj = 0; nj < 4; nj++)
                acc[mi][nj] = __builtin_amdgcn_mfma_f32_16x16x32_bf16(
                    af[mi], bfr[nj], acc[mi][nj], 0, 0, 0);
    }

    // epilogue: C/D layout col=lane&15, row=(lane>>4)*4+reg  [verified m89/m91]
#pragma unroll
    for (int mi = 0; mi < 4; mi++)
#pragma unroll
        for (int nj = 0; nj < 4; nj++) {
            int rbase = bm * GBM + wm * 64 + mi * 16 + g * 4;
            int col   = bn * GBN + wn * 64 + nj * 16 + l16;
#pragma unroll
            for (int r = 0; r < 4; r++) {
                float v = acc[mi][nj][r];
                size_t off = (size_t)(rbase + r) * N + col;
                if (OUTF32) Cf[off] = v;
                else        Cb[off] = f2bf(v);
            }
        }
}

// ---------------- Flash attention (causal, GQA) -------------------------------
// grid: (T/64, NH, B). block: 256 thr = 4 waves; wave w owns q rows qb+16w..+15.
#define QB 64
#define KB 32
#define VTS 40   // Vt row stride (32 kp + pad)
#define PS  36   // P row stride (32 kp + pad)

__global__ __launch_bounds__(256) void attn_kernel(const ushort_t* __restrict__ qkv,
                                                   ushort_t* __restrict__ aout) {
    __shared__ alignas(16) ushort_t Ks[KB * HD];     // [kp][d], XOR-swizzled
    __shared__ alignas(16) ushort_t Vt[HD * VTS];    // [d][kp] transposed
    __shared__ alignas(16) ushort_t Ps[4][16 * PS];  // per-wave P bounce

    const int tid = threadIdx.x;
    const int lane = tid & 63, wid = tid >> 6;
    const int g = lane >> 4, l16 = lane & 15;
    const int qb = blockIdx.x * QB;
    const int h  = blockIdx.y;
    const int b  = blockIdx.z;
    const int hk = h >> 2;                 // repeat_interleave: kv head = h/4
    const size_t rowbase = (size_t)b * TT;

    const ushort_t* kg = qkv + TC + hk * HD;
    const ushort_t* vg = qkv + TC + KVDIM + hk * HD;

    const int q0 = qb + wid * 16;

    // Q fragments (A-operand), held for the whole block
    bf16x8 qa[4];
    {
        const ushort_t* qp = qkv + (rowbase + q0 + l16) * NQKV + h * HD + g * 8;
#pragma unroll
        for (int c = 0; c < 4; c++)
            qa[c] = *reinterpret_cast<const bf16x8*>(qp + c * 32);
    }

    f32x4 oacc[8] = {};
    float m2[4], lsum[4];
#pragma unroll
    for (int r = 0; r < 4; r++) { m2[r] = -1e30f; lsum[r] = 0.f; }

    const float sc = 0.08838834764831845f * 1.4426950408889634f; // 1/sqrt(128)*log2e
    const int ntiles = (qb + QB) / KB;

    for (int t = 0; t < ntiles; ++t) {
        const int kp0 = t * KB;
        // ---- stage K (row-major, swizzled) and V (transposed) ----
        {
            int kp = tid >> 3;
            int d0 = (tid & 7) * 16;
            const ushort_t* src = kg + (rowbase + kp0 + kp) * NQKV + d0;
            us8 k0 = *reinterpret_cast<const us8*>(src);
            us8 k1 = *reinterpret_cast<const us8*>(src + 8);
            int vd  = tid & 127;
            int vkg = tid >> 7;
            const ushort_t* vsrc = vg + (rowbase + kp0 + vkg * 16) * NQKV + vd;
            ushort_t vv[16];
#pragma unroll
            for (int j = 0; j < 16; j++) vv[j] = vsrc[(size_t)j * NQKV];

            __syncthreads();             // previous tile's compute done
            int base = kp * HD + d0;
            int s2   = (kp & 7) << 3;
            *reinterpret_cast<us8*>(&Ks[base ^ s2])       = k0;
            *reinterpret_cast<us8*>(&Ks[(base + 8) ^ s2]) = k1;
            us8 w0, w1;
#pragma unroll
            for (int j = 0; j < 8; j++) { w0[j] = vv[j]; w1[j] = vv[8 + j]; }
            *reinterpret_cast<us8*>(&Vt[vd * VTS + vkg * 16])     = w0;
            *reinterpret_cast<us8*>(&Vt[vd * VTS + vkg * 16 + 8]) = w1;
            __syncthreads();
        }

        if (kp0 <= q0 + 15) {            // wave-uniform causal tile skip
            // ---- S = Q K^T (two 16-col fragments) ----
            f32x4 s[2] = {};
#pragma unroll
            for (int fj = 0; fj < 2; fj++) {
                int kp = fj * 16 + l16;
#pragma unroll
                for (int c = 0; c < 4; c++) {
                    int ix = (kp * HD + c * 32 + g * 8) ^ ((kp & 7) << 3);
                    bf16x8 kb = *reinterpret_cast<const bf16x8*>(&Ks[ix]);
                    s[fj] = __builtin_amdgcn_mfma_f32_16x16x32_bf16(qa[c], kb, s[fj], 0, 0, 0);
                }
            }
            // ---- online softmax (base-2 domain), rows = g*4+r ----
            float alpha[4];
#pragma unroll
            for (int r = 0; r < 4; r++) {
                int qrow = q0 + g * 4 + r;
                float v0 = (kp0 + l16      <= qrow) ? s[0][r] * sc : -1e30f;
                float v1 = (kp0 + 16 + l16 <= qrow) ? s[1][r] * sc : -1e30f;
                s[0][r] = v0; s[1][r] = v1;
                float mx = fmaxf(v0, v1);
#pragma unroll
                for (int off = 1; off < 16; off <<= 1)
                    mx = fmaxf(mx, __shfl_xor(mx, off));
                float mn = fmaxf(m2[r], mx);
                alpha[r] = exp2f(m2[r] - mn);
                m2[r] = mn;
            }
#pragma unroll
            for (int c = 0; c < 8; c++)
#pragma unroll
                for (int r = 0; r < 4; r++) oacc[c][r] *= alpha[r];
#pragma unroll
            for (int r = 0; r < 4; r++) {
                float p0 = exp2f(s[0][r] - m2[r]);
                float p1 = exp2f(s[1][r] - m2[r]);
                s[0][r] = p0; s[1][r] = p1;
                float ps = p0 + p1;
#pragma unroll
                for (int off = 1; off < 16; off <<= 1)
                    ps += __shfl_xor(ps, off);
                lsum[r] = lsum[r] * alpha[r] + ps;
            }
            // ---- P -> LDS (C-layout) then read back as A-fragment ----
#pragma unroll
            for (int fj = 0; fj < 2; fj++)
#pragma unroll
                for (int r = 0; r < 4; r++)
                    Ps[wid][(g * 4 + r) * PS + fj * 16 + l16] = f2bf(s[fj][r]);
            asm volatile("s_waitcnt lgkmcnt(0)" ::: "memory");
            bf16x4 plo = *reinterpret_cast<const bf16x4*>(&Ps[wid][l16 * PS + g * 8]);
            bf16x4 phi = *reinterpret_cast<const bf16x4*>(&Ps[wid][l16 * PS + g * 8 + 4]);
            bf16x8 pa;
#pragma unroll
            for (int e = 0; e < 4; e++) { pa[e] = plo[e]; pa[4 + e] = phi[e]; }
            // ---- O += P V ----
#pragma unroll
            for (int c = 0; c < 8; c++) {
                bf16x8 vb = *reinterpret_cast<const bf16x8*>(&Vt[(c * 16 + l16) * VTS + g * 8]);
                oacc[c] = __builtin_amdgcn_mfma_f32_16x16x32_bf16(pa, vb, oacc[c], 0, 0, 0);
            }
        }
    }

    // ---- epilogue: normalize and store bf16 ----
    float rl[4];
#pragma unroll
    for (int r = 0; r < 4; r++) rl[r] = 1.f / lsum[r];
#pragma unroll
    for (int c = 0; c < 8; c++)
#pragma unroll
        for (int r = 0; r < 4; r++) {
            int qrow = q0 + g * 4 + r;
            aout[(rowbase + qrow) * TC + h * HD + c * 16 + l16] = f2bf(oacc[c][r] * rl[r]);
        }
}

// ---------------- launch ------------------------------------------------------
extern "C" void kernel_launch(void* const* d_in, const int* in_sizes, int n_in,
                              void* d_out, int out_size, void* d_ws, size_t ws_size,
                              hipStream_t stream) {
    const float* x  = (const float*)d_in[0];
    const float* Wq = (const float*)d_in[1];
    const float* Wk = (const float*)d_in[2];
    const float* Wv = (const float*)d_in[3];
    const float* Wo = (const float*)d_in[4];
    float* out = (float*)d_out;

    ushort_t* x_bf  = (ushort_t*)d_ws;                      // 16.78M el
    ushort_t* wqkv  = x_bf  + (size_t)MTOK * TC;            // 3072*2048
    ushort_t* wo_bf = wqkv  + (size_t)NQKV * TC;            // 2048*2048
    ushort_t* qkv   = wo_bf + (size_t)TC * TC;              // 8192*3072
    ushort_t* attn  = x_bf;                                  // alias: x dead after QKV GEMM

    auto nb = [](long n) { long b = (n / 4 + 255) / 256; return (int)(b > 4096 ? 4096 : b); };

    cast_bf16<<<nb((long)MTOK * TC), 256, 0, stream>>>(x, x_bf, (long)MTOK * TC);
    cast_bf16<<<nb((long)TC * TC),   256, 0, stream>>>(Wq, wqkv, (long)TC * TC);
    cast_bf16<<<nb((long)KVDIM * TC),256, 0, stream>>>(Wk, wqkv + (size_t)TC * TC, (long)KVDIM * TC);
    cast_bf16<<<nb((long)KVDIM * TC),256, 0, stream>>>(Wv, wqkv + (size_t)(TC + KVDIM) * TC, (long)KVDIM * TC);
    cast_bf16<<<nb((long)TC * TC),   256, 0, stream>>>(Wo, wo_bf, (long)TC * TC);

    dim3 gq(NQKV / GBN, MTOK / GBM);
    gemm_bt<false><<<gq, 256, 0, stream>>>(x_bf, wqkv, nullptr, qkv, MTOK, NQKV, TC);

    attn_kernel<<<dim3(TT / QB, NH, TB), 256, 0, stream>>>(qkv, attn);

    dim3 go(TC / GBN, MTOK / GBM);
    gemm_bt<true><<<go, 256, 0, stream>>>(attn, wo_bf, out, nullptr, MTOK, TC, TC);
}

// Round 3
// 531.370 us; speedup vs baseline: 1.3536x; 1.3536x over previous
//
#include <hip/hip_runtime.h>

#define TB 4
#define TT 2048
#define TC 2048
#define NH 16
#define NKV 4
#define HD 128
#define KVDIM (NKV*HD)        // 512
#define NQKV (TC + 2*KVDIM)   // 3072
#define MTOK (TB*TT)          // 8192

typedef __bf16 bf16x8 __attribute__((ext_vector_type(8)));
typedef float  f32x4  __attribute__((ext_vector_type(4)));
typedef float  f32x16 __attribute__((ext_vector_type(16)));
typedef unsigned short ushort_t;
typedef unsigned short us8 __attribute__((ext_vector_type(8)));
typedef unsigned short us4 __attribute__((ext_vector_type(4)));
typedef unsigned int u32x4 __attribute__((ext_vector_type(4)));

// 1/sqrt(128) * log2(e)  (folded into Q during the QKV GEMM epilogue)
#define QSC 0.12751743f

__device__ __forceinline__ ushort_t f2bf(float f) {
    unsigned u = __builtin_bit_cast(unsigned, f);
    u += 0x7fffu + ((u >> 16) & 1u);
    return (ushort_t)(u >> 16);
}

// ---------------- cast f32 -> bf16 (vectorized, grid-stride) ----------------
__global__ __launch_bounds__(256) void cast_bf16(const float* __restrict__ in,
                                                 ushort_t* __restrict__ out, long n) {
    long i = (long)blockIdx.x * blockDim.x + threadIdx.x;
    long stride = (long)gridDim.x * blockDim.x;
    for (long e = i * 4; e < n; e += stride * 4) {
        float4 v = *reinterpret_cast<const float4*>(in + e);
        us4 o;
        o[0] = f2bf(v.x); o[1] = f2bf(v.y); o[2] = f2bf(v.z); o[3] = f2bf(v.w);
        *reinterpret_cast<us4*>(out + e) = o;
    }
}

// ---------------- GEMM: C[M][N] = A[M][K](bf16) * Bw[N][K](bf16)^T -----------
#define GBM 128
#define GBN 128
#define GBK 32

template<bool OUTF32, bool QSCALE>
__global__ __launch_bounds__(256) void gemm_bt(const ushort_t* __restrict__ A,
                                               const ushort_t* __restrict__ Bw,
                                               float* __restrict__ Cf,
                                               ushort_t* __restrict__ Cb,
                                               int M, int N, int K) {
    __shared__ alignas(16) ushort_t As[GBM * GBK];
    __shared__ alignas(16) ushort_t Bs[GBN * GBK];

    const int tid = threadIdx.x;
    const int bm = blockIdx.y, bn = blockIdx.x;
    const int lane = tid & 63, wid = tid >> 6;
    const int wm = wid >> 1, wn = wid & 1;
    const int g = lane >> 4, l16 = lane & 15;

    f32x4 acc[4][4] = {};

    const int srow = tid >> 1;
    const int scol = (tid & 1) * 16;
    const ushort_t* Ag = A  + (size_t)(bm * GBM + srow) * K + scol;
    const ushort_t* Bg = Bw + (size_t)(bn * GBN + srow) * K + scol;
    const int wix  = srow * GBK + scol;
    const int sw   = (srow & 3) << 3;
    const int wsw0 = wix ^ sw;
    const int wsw1 = (wix + 8) ^ sw;

    for (int kt = 0; kt < K; kt += GBK) {
        us8 a0 = *reinterpret_cast<const us8*>(Ag + kt);
        us8 a1 = *reinterpret_cast<const us8*>(Ag + kt + 8);
        us8 b0 = *reinterpret_cast<const us8*>(Bg + kt);
        us8 b1 = *reinterpret_cast<const us8*>(Bg + kt + 8);
        __syncthreads();
        *reinterpret_cast<us8*>(&As[wsw0]) = a0;
        *reinterpret_cast<us8*>(&As[wsw1]) = a1;
        *reinterpret_cast<us8*>(&Bs[wsw0]) = b0;
        *reinterpret_cast<us8*>(&Bs[wsw1]) = b1;
        __syncthreads();

        bf16x8 af[4], bfr[4];
#pragma unroll
        for (int mi = 0; mi < 4; mi++) {
            int row = wm * 64 + mi * 16 + l16;
            int ix = (row * GBK + g * 8) ^ ((row & 3) << 3);
            af[mi] = *reinterpret_cast<const bf16x8*>(&As[ix]);
        }
#pragma unroll
        for (int nj = 0; nj < 4; nj++) {
            int row = wn * 64 + nj * 16 + l16;
            int ix = (row * GBK + g * 8) ^ ((row & 3) << 3);
            bfr[nj] = *reinterpret_cast<const bf16x8*>(&Bs[ix]);
        }
#pragma unroll
        for (int mi = 0; mi < 4; mi++)
#pragma unroll
            for (int nj = 0; nj < 4; nj++)
                acc[mi][nj] = __builtin_amdgcn_mfma_f32_16x16x32_bf16(
                    af[mi], bfr[nj], acc[mi][nj], 0, 0, 0);
    }

#pragma unroll
    for (int mi = 0; mi < 4; mi++)
#pragma unroll
        for (int nj = 0; nj < 4; nj++) {
            int rbase = bm * GBM + wm * 64 + mi * 16 + g * 4;
            int col   = bn * GBN + wn * 64 + nj * 16 + l16;
#pragma unroll
            for (int r = 0; r < 4; r++) {
                float v = acc[mi][nj][r];
                if (QSCALE && col < TC) v *= QSC;
                size_t off = (size_t)(rbase + r) * N + col;
                if (OUTF32) Cf[off] = v;
                else        Cb[off] = f2bf(v);
            }
        }
}

// ---------------- Flash attention (causal, GQA), 32x32 swapped-QK ------------
// grid: (T/128, NH, B). block: 256 thr = 4 waves; wave w owns q rows q0..q0+31.
// QK^T: mfma(K,Q) -> S^T (col=q, row=kp). PV: mfma(V^T, P^T) -> O^T (col=q,
// row=d) so per-lane softmax state (q = lane&31) matches accumulator columns.
#define AQB 128
#define AKB 64
#define VTS 72   // Vt row stride in elements (odd multiple of 16B -> uniform spans)

__global__ __launch_bounds__(256, 3) void attn_kernel(const ushort_t* __restrict__ qkv,
                                                      ushort_t* __restrict__ aout) {
    __shared__ alignas(16) ushort_t Ks[AKB * HD];    // [kp][d], XOR-swizzled
    __shared__ alignas(16) ushort_t Vt[HD * VTS];    // [d][kp] transposed

    const int tid  = threadIdx.x;
    const int lane = tid & 63, wid = tid >> 6;
    const int hi   = lane >> 5, l31 = lane & 31;
    const int bidx = gridDim.x - 1 - blockIdx.x;     // heavy (large-qb) blocks first
    const int qb   = bidx * AQB;
    const int h    = blockIdx.y;
    const int b    = blockIdx.z;
    const int hk   = h >> 2;                         // GQA: kv head = h/4
    const size_t rowbase = (size_t)b * TT;
    const int q0   = qb + wid * 32;
    const int qrow = q0 + l31;

    // Q as B-operand fragments (pre-scaled); col = lane&31 -> q, k-dim = d
    bf16x8 qfr[8];
    {
        const ushort_t* qp = qkv + (rowbase + qrow) * NQKV + h * HD + hi * 8;
#pragma unroll
        for (int s = 0; s < 8; s++)
            qfr[s] = *reinterpret_cast<const bf16x8*>(qp + s * 16);
    }

    f32x16 oacc[4];
#pragma unroll
    for (int d = 0; d < 4; d++)
#pragma unroll
        for (int r = 0; r < 16; r++) oacc[d][r] = 0.f;
    float mrun = -1e30f, lsum = 0.f;

    const ushort_t* kg = qkv + TC + hk * HD;
    const ushort_t* vg = qkv + TC + KVDIM + hk * HD;
    const int ntiles = (qb + AQB) / AKB;
    const int rswz = (l31 & 7) << 3;

    for (int t = 0; t < ntiles; ++t) {
        const int kp0 = t * AKB;
        // ---- stage K (row-major swizzled) + V (transposed) ----
        {
            const int kr = tid >> 2, dc = (tid & 3) * 32;
            const ushort_t* ksrc = kg + (rowbase + kp0 + kr) * NQKV + dc;
            us8 k0 = *reinterpret_cast<const us8*>(ksrc);
            us8 k1 = *reinterpret_cast<const us8*>(ksrc + 8);
            us8 k2 = *reinterpret_cast<const us8*>(ksrc + 16);
            us8 k3 = *reinterpret_cast<const us8*>(ksrc + 24);
            const int vd = tid & 127, vh = tid >> 7;
            const ushort_t* vsrc = vg + (rowbase + kp0 + vh * 32) * NQKV + vd;
            ushort_t vv[32];
#pragma unroll
            for (int j = 0; j < 32; j++) vv[j] = vsrc[(size_t)j * NQKV];
            __syncthreads();             // previous tile's LDS reads done
            const int kb = kr * HD + dc, ksw = (kr & 7) << 3;
            *reinterpret_cast<us8*>(&Ks[(kb     ) ^ ksw]) = k0;
            *reinterpret_cast<us8*>(&Ks[(kb +  8) ^ ksw]) = k1;
            *reinterpret_cast<us8*>(&Ks[(kb + 16) ^ ksw]) = k2;
            *reinterpret_cast<us8*>(&Ks[(kb + 24) ^ ksw]) = k3;
#pragma unroll
            for (int mq = 0; mq < 4; mq++) {
                us8 w;
#pragma unroll
                for (int e = 0; e < 8; e++) w[e] = vv[mq * 8 + e];
                *reinterpret_cast<us8*>(&Vt[vd * VTS + vh * 32 + mq * 8]) = w;
            }
            __syncthreads();
        }

        if (kp0 <= q0 + 31) {            // wave-uniform causal tile skip
            // ---- S^T = K Q^T : col=lane&31 -> q, row crow(r,hi) -> kp ----
            f32x16 s0, s1;
#pragma unroll
            for (int r = 0; r < 16; r++) { s0[r] = 0.f; s1[r] = 0.f; }
#pragma unroll
            for (int ds = 0; ds < 8; ds++) {
                bf16x8 ka = *reinterpret_cast<const bf16x8*>(
                    &Ks[(l31 * HD + ds * 16 + hi * 8) ^ rswz]);
                s0 = __builtin_amdgcn_mfma_f32_32x32x16_bf16(ka, qfr[ds], s0, 0, 0, 0);
            }
#pragma unroll
            for (int ds = 0; ds < 8; ds++) {
                bf16x8 ka = *reinterpret_cast<const bf16x8*>(
                    &Ks[((32 + l31) * HD + ds * 16 + hi * 8) ^ rswz]);
                s1 = __builtin_amdgcn_mfma_f32_32x32x16_bf16(ka, qfr[ds], s1, 0, 0, 0);
            }
            // ---- causal mask (diagonal tiles only; wave-uniform branch) ----
            if (kp0 + 63 > q0) {
#pragma unroll
                for (int r = 0; r < 16; r++) {
                    int k0i = kp0 + (r & 3) + 8 * (r >> 2) + 4 * hi;
                    if (k0i > qrow)      s0[r] = -1e30f;
                    if (k0i + 32 > qrow) s1[r] = -1e30f;
                }
            }
            // ---- row max: 31 in-lane fmax + one lane^32 exchange ----
            float mx = fmaxf(s0[0], s1[0]);
#pragma unroll
            for (int r = 1; r < 16; r++) mx = fmaxf(mx, fmaxf(s0[r], s1[r]));
            mx = fmaxf(mx, __shfl_xor(mx, 32));
            // ---- defer-max rescale (T13, THR=8 in base-2 domain) ----
            if (!__all(mx <= mrun + 8.f)) {
                float mn = fmaxf(mrun, mx);
                float al = exp2f(mrun - mn);
#pragma unroll
                for (int d = 0; d < 4; d++)
#pragma unroll
                    for (int r = 0; r < 16; r++) oacc[d][r] *= al;
                lsum *= al;
                mrun = mn;
            }
            // ---- P = 2^(S-m), bf16-pack pairs, row-sum ----
            unsigned pk0[8], pk1[8];
            float ps = 0.f;
#pragma unroll
            for (int w = 0; w < 8; w++) {
                float a0 = exp2f(s0[2 * w] - mrun), a1 = exp2f(s0[2 * w + 1] - mrun);
                float b0 = exp2f(s1[2 * w] - mrun), b1 = exp2f(s1[2 * w + 1] - mrun);
                ps += (a0 + a1) + (b0 + b1);
                pk0[w] = (unsigned)f2bf(a0) | ((unsigned)f2bf(a1) << 16);
                pk1[w] = (unsigned)f2bf(b0) | ((unsigned)f2bf(b1) << 16);
            }
            ps += __shfl_xor(ps, 32);
            lsum += ps;
            // ---- O^T += V^T P^T : build P-frag per k-slot via lane^32 swap ----
#pragma unroll
            for (int ks = 0; ks < 4; ks++) {
                const unsigned* pkt = (ks < 2) ? pk0 : pk1;   // kt = ks>>1 (uniform)
                unsigned c00 = pkt[4 * (ks & 1) + 0];
                unsigned c01 = pkt[4 * (ks & 1) + 1];
                unsigned c10 = pkt[4 * (ks & 1) + 2];
                unsigned c11 = pkt[4 * (ks & 1) + 3];
                unsigned out0 = hi ? c00 : c10;   // send what partner needs
                unsigned out1 = hi ? c01 : c11;
                unsigned rc0 = __shfl_xor(out0, 32);
                unsigned rc1 = __shfl_xor(out1, 32);
                u32x4 faw;
                faw[0] = hi ? rc0 : c00;          // k = 16ks+8hi+{0,1}
                faw[1] = hi ? rc1 : c01;          // {2,3}
                faw[2] = hi ? c10 : rc0;          // {4,5}
                faw[3] = hi ? c11 : rc1;          // {6,7}
                bf16x8 pa = __builtin_bit_cast(bf16x8, faw);
#pragma unroll
                for (int dt = 0; dt < 4; dt++) {
                    bf16x8 vb = *reinterpret_cast<const bf16x8*>(
                        &Vt[(dt * 32 + l31) * VTS + ks * 16 + hi * 8]);
                    // V^T as A-operand, P^T as B-operand -> D col = q = lane&31
                    oacc[dt] = __builtin_amdgcn_mfma_f32_32x32x16_bf16(vb, pa, oacc[dt], 0, 0, 0);
                }
            }
        }
    }

    // ---- epilogue: normalize, pack pairs, store (d = 32dt + crow(r,hi)) ----
    const float rl = 1.f / lsum;
    ushort_t* orow = aout + (rowbase + qrow) * TC + h * HD;
#pragma unroll
    for (int dt = 0; dt < 4; dt++)
#pragma unroll
        for (int rp = 0; rp < 8; rp++) {
            int d = dt * 32 + ((2 * rp) & 3) + 8 * ((2 * rp) >> 2) + 4 * hi;
            unsigned w = (unsigned)f2bf(oacc[dt][2 * rp] * rl)
                       | ((unsigned)f2bf(oacc[dt][2 * rp + 1] * rl) << 16);
            *reinterpret_cast<unsigned*>(orow + d) = w;
        }
}

// ---------------- launch ------------------------------------------------------
extern "C" void kernel_launch(void* const* d_in, const int* in_sizes, int n_in,
                              void* d_out, int out_size, void* d_ws, size_t ws_size,
                              hipStream_t stream) {
    const float* x  = (const float*)d_in[0];
    const float* Wq = (const float*)d_in[1];
    const float* Wk = (const float*)d_in[2];
    const float* Wv = (const float*)d_in[3];
    const float* Wo = (const float*)d_in[4];
    float* out = (float*)d_out;

    ushort_t* x_bf  = (ushort_t*)d_ws;
    ushort_t* wqkv  = x_bf  + (size_t)MTOK * TC;
    ushort_t* wo_bf = wqkv  + (size_t)NQKV * TC;
    ushort_t* qkv   = wo_bf + (size_t)TC * TC;
    ushort_t* attn  = x_bf;                          // alias: x dead after QKV GEMM

    auto nb = [](long n) { long b = (n / 4 + 255) / 256; return (int)(b > 4096 ? 4096 : b); };

    cast_bf16<<<nb((long)MTOK * TC), 256, 0, stream>>>(x, x_bf, (long)MTOK * TC);
    cast_bf16<<<nb((long)TC * TC),   256, 0, stream>>>(Wq, wqkv, (long)TC * TC);
    cast_bf16<<<nb((long)KVDIM * TC),256, 0, stream>>>(Wk, wqkv + (size_t)TC * TC, (long)KVDIM * TC);
    cast_bf16<<<nb((long)KVDIM * TC),256, 0, stream>>>(Wv, wqkv + (size_t)(TC + KVDIM) * TC, (long)KVDIM * TC);
    cast_bf16<<<nb((long)TC * TC),   256, 0, stream>>>(Wo, wo_bf, (long)TC * TC);

    dim3 gq(NQKV / GBN, MTOK / GBM);
    gemm_bt<false, true><<<gq, 256, 0, stream>>>(x_bf, wqkv, nullptr, qkv, MTOK, NQKV, TC);

    attn_kernel<<<dim3(TT / AQB, NH, TB), 256, 0, stream>>>(qkv, attn);

    dim3 go(TC / GBN, MTOK / GBM);
    gemm_bt<true, false><<<go, 256, 0, stream>>>(attn, wo_bf, out, nullptr, MTOK, TC, TC);
}

// Round 4
// 406.439 us; speedup vs baseline: 1.7697x; 1.3074x over previous
//
#include <hip/hip_runtime.h>

#define TB 4
#define TT 2048
#define TC 2048
#define NH 16
#define NKV 4
#define HD 128
#define KVDIM (NKV*HD)        // 512
#define NQKV (TC + 2*KVDIM)   // 3072
#define MTOK (TB*TT)          // 8192

typedef __bf16 bf16x8 __attribute__((ext_vector_type(8)));
typedef float  f32x4  __attribute__((ext_vector_type(4)));
typedef float  f32x16 __attribute__((ext_vector_type(16)));
typedef unsigned short ushort_t;
typedef unsigned short us8 __attribute__((ext_vector_type(8)));
typedef unsigned short us4 __attribute__((ext_vector_type(4)));
typedef unsigned int u32x4 __attribute__((ext_vector_type(4)));

// 1/sqrt(128) * log2(e)  (folded into Q during the QKV GEMM epilogue)
#define QSC 0.12751743f

__device__ __forceinline__ ushort_t f2bf(float f) {
    unsigned u = __builtin_bit_cast(unsigned, f);
    u += 0x7fffu + ((u >> 16) & 1u);
    return (ushort_t)(u >> 16);
}

// ---------------- cast f32 -> bf16 (vectorized, grid-stride) ----------------
__global__ __launch_bounds__(256) void cast_bf16(const float* __restrict__ in,
                                                 ushort_t* __restrict__ out, long n) {
    long i = (long)blockIdx.x * blockDim.x + threadIdx.x;
    long stride = (long)gridDim.x * blockDim.x;
    for (long e = i * 4; e < n; e += stride * 4) {
        float4 v = *reinterpret_cast<const float4*>(in + e);
        us4 o;
        o[0] = f2bf(v.x); o[1] = f2bf(v.y); o[2] = f2bf(v.z); o[3] = f2bf(v.w);
        *reinterpret_cast<us4*>(out + e) = o;
    }
}

// ---------------- GEMM: C[M][N] = A[M][K](bf16) * Bw[N][K](bf16)^T -----------
#define GBM 128
#define GBN 128
#define GBK 32

template<bool OUTF32, bool QSCALE>
__global__ __launch_bounds__(256) void gemm_bt(const ushort_t* __restrict__ A,
                                               const ushort_t* __restrict__ Bw,
                                               float* __restrict__ Cf,
                                               ushort_t* __restrict__ Cb,
                                               int M, int N, int K) {
    __shared__ alignas(16) ushort_t As[GBM * GBK];
    __shared__ alignas(16) ushort_t Bs[GBN * GBK];

    const int tid = threadIdx.x;
    const int bm = blockIdx.y, bn = blockIdx.x;
    const int lane = tid & 63, wid = tid >> 6;
    const int wm = wid >> 1, wn = wid & 1;
    const int g = lane >> 4, l16 = lane & 15;

    f32x4 acc[4][4] = {};

    const int srow = tid >> 1;
    const int scol = (tid & 1) * 16;
    const ushort_t* Ag = A  + (size_t)(bm * GBM + srow) * K + scol;
    const ushort_t* Bg = Bw + (size_t)(bn * GBN + srow) * K + scol;
    const int wix  = srow * GBK + scol;
    const int sw   = (srow & 3) << 3;
    const int wsw0 = wix ^ sw;
    const int wsw1 = (wix + 8) ^ sw;

    for (int kt = 0; kt < K; kt += GBK) {
        us8 a0 = *reinterpret_cast<const us8*>(Ag + kt);
        us8 a1 = *reinterpret_cast<const us8*>(Ag + kt + 8);
        us8 b0 = *reinterpret_cast<const us8*>(Bg + kt);
        us8 b1 = *reinterpret_cast<const us8*>(Bg + kt + 8);
        __syncthreads();
        *reinterpret_cast<us8*>(&As[wsw0]) = a0;
        *reinterpret_cast<us8*>(&As[wsw1]) = a1;
        *reinterpret_cast<us8*>(&Bs[wsw0]) = b0;
        *reinterpret_cast<us8*>(&Bs[wsw1]) = b1;
        __syncthreads();

        bf16x8 af[4], bfr[4];
#pragma unroll
        for (int mi = 0; mi < 4; mi++) {
            int row = wm * 64 + mi * 16 + l16;
            int ix = (row * GBK + g * 8) ^ ((row & 3) << 3);
            af[mi] = *reinterpret_cast<const bf16x8*>(&As[ix]);
        }
#pragma unroll
        for (int nj = 0; nj < 4; nj++) {
            int row = wn * 64 + nj * 16 + l16;
            int ix = (row * GBK + g * 8) ^ ((row & 3) << 3);
            bfr[nj] = *reinterpret_cast<const bf16x8*>(&Bs[ix]);
        }
#pragma unroll
        for (int mi = 0; mi < 4; mi++)
#pragma unroll
            for (int nj = 0; nj < 4; nj++)
                acc[mi][nj] = __builtin_amdgcn_mfma_f32_16x16x32_bf16(
                    af[mi], bfr[nj], acc[mi][nj], 0, 0, 0);
    }

#pragma unroll
    for (int mi = 0; mi < 4; mi++)
#pragma unroll
        for (int nj = 0; nj < 4; nj++) {
            int rbase = bm * GBM + wm * 64 + mi * 16 + g * 4;
            int col   = bn * GBN + wn * 64 + nj * 16 + l16;
#pragma unroll
            for (int r = 0; r < 4; r++) {
                float v = acc[mi][nj][r];
                if (QSCALE && col < TC) v *= QSC;
                size_t off = (size_t)(rbase + r) * N + col;
                if (OUTF32) Cf[off] = v;
                else        Cb[off] = f2bf(v);
            }
        }
}

// ---------------- Flash attention (causal, GQA), 32x32 swapped-QK ------------
// grid: (8, NH, B); block processes q-tile pair {15-gx, gx} (uniform 34 K-tiles).
// Double-buffered LDS, loads for t+1 issued before compute of t (T14).
// QK^T: mfma(K,Q) -> S^T (col=q, row=kp). PV: mfma(V^T, P^T) -> O^T (col=q,
// row=d) so per-lane softmax state (q = lane&31) matches accumulator columns.
#define AQB 128
#define AKB 64
#define NTB (TT/AQB)   // 16 q-tiles
#define VTS 72         // Vt row stride (mult of 8 -> 16B rows; banks via XOR swz)

__global__ __launch_bounds__(256, 2) void attn_kernel(const ushort_t* __restrict__ qkv,
                                                      ushort_t* __restrict__ aout) {
    __shared__ alignas(16) ushort_t Ks[2][AKB * HD];   // [kp][d], XOR-swizzled
    __shared__ alignas(16) ushort_t Vt[2][HD * VTS];   // [d][kp], granule-XOR swz

    const int tid  = threadIdx.x;
    const int lane = tid & 63, wid = tid >> 6;
    const int hi   = lane >> 5, l31 = lane & 31;
    const int gx   = blockIdx.x;                 // 0..7
    const int h    = blockIdx.y;
    const int b    = blockIdx.z;
    const int hk   = h >> 2;                     // GQA: kv head = h/4
    const size_t rowbase = (size_t)b * TT;

    const ushort_t* kg = qkv + TC + hk * HD;
    const ushort_t* vg = qkv + TC + KVDIM + hk * HD;
    const int rswz = (l31 & 7) << 3;

    // staging registers (live across the pipeline)
    us8 sk0, sk1, sk2, sk3;
    unsigned vv2[16];
    const int kr = tid >> 2, dc = (tid & 3) * 32;   // K: row, d-col base
    const int vs = ((lane >> 2) & 7) << 3;          // V-write granule swizzle

    for (int phase = 0; phase < 2; ++phase) {
        const int qb = (phase == 0 ? (NTB - 1 - gx) : gx) * AQB;
        const int q0 = qb + wid * 32;
        const int qrow = q0 + l31;

        // Q as B-operand fragments (pre-scaled); col = lane&31 -> q, k-dim = d
        bf16x8 qfr[8];
        {
            const ushort_t* qp = qkv + (rowbase + qrow) * NQKV + h * HD + hi * 8;
#pragma unroll
            for (int s = 0; s < 8; s++)
                qfr[s] = *reinterpret_cast<const bf16x8*>(qp + s * 16);
        }

        f32x16 oacc[4];
#pragma unroll
        for (int d = 0; d < 4; d++)
#pragma unroll
            for (int r = 0; r < 16; r++) oacc[d][r] = 0.f;
        float mrun = -1e30f, lsum = 0.f;

        const int ntiles = qb / AKB + 2;

        // ---- issue loads for tile 0 (into registers) ----
        {
            const ushort_t* ksrc = kg + (rowbase + kr) * NQKV + dc;
            sk0 = *reinterpret_cast<const us8*>(ksrc);
            sk1 = *reinterpret_cast<const us8*>(ksrc + 8);
            sk2 = *reinterpret_cast<const us8*>(ksrc + 16);
            sk3 = *reinterpret_cast<const us8*>(ksrc + 24);
            const ushort_t* vsrc = vg + (rowbase + wid * 16) * NQKV + 2 * lane;
#pragma unroll
            for (int j = 0; j < 16; j++)
                vv2[j] = *reinterpret_cast<const unsigned*>(vsrc + (size_t)j * NQKV);
        }
        if (phase) __syncthreads();     // protect LDS reuse across phases

        for (int t = 0; t < ntiles; ++t) {
            const int kp0 = t * AKB;
            const int cur = t & 1;
            // ---- write staged regs -> LDS buf[cur] ----
            {
                const int kb = kr * HD + dc, ksw = (kr & 7) << 3;
                *reinterpret_cast<us8*>(&Ks[cur][(kb     ) ^ ksw]) = sk0;
                *reinterpret_cast<us8*>(&Ks[cur][(kb +  8) ^ ksw]) = sk1;
                *reinterpret_cast<us8*>(&Ks[cur][(kb + 16) ^ ksw]) = sk2;
                *reinterpret_cast<us8*>(&Ks[cur][(kb + 24) ^ ksw]) = sk3;
                // pack d-pair rows: lo = row 2*lane, hi = row 2*lane+1
                u32x4 pl0, pl1, ph0, ph1;
#pragma unroll
                for (int k = 0; k < 4; k++) {
                    unsigned a = vv2[2 * k], c = vv2[2 * k + 1];
                    pl0[k] = (a & 0xffffu) | (c << 16);
                    ph0[k] = (a >> 16) | (c & 0xffff0000u);
                    unsigned a2 = vv2[8 + 2 * k], c2 = vv2[8 + 2 * k + 1];
                    pl1[k] = (a2 & 0xffffu) | (c2 << 16);
                    ph1[k] = (a2 >> 16) | (c2 & 0xffff0000u);
                }
                ushort_t* r0 = &Vt[cur][(2 * lane) * VTS];
                ushort_t* r1 = &Vt[cur][(2 * lane + 1) * VTS];
                const int o0 = (wid * 16) ^ vs, o1 = (wid * 16 + 8) ^ vs;
                *reinterpret_cast<u32x4*>(r0 + o0) = pl0;
                *reinterpret_cast<u32x4*>(r0 + o1) = pl1;
                *reinterpret_cast<u32x4*>(r1 + o0) = ph0;
                *reinterpret_cast<u32x4*>(r1 + o1) = ph1;
            }
            // ---- issue loads for tile t+1 ----
            if (t + 1 < ntiles) {
                const int kn = (t + 1) * AKB;
                const ushort_t* ksrc = kg + (rowbase + kn + kr) * NQKV + dc;
                sk0 = *reinterpret_cast<const us8*>(ksrc);
                sk1 = *reinterpret_cast<const us8*>(ksrc + 8);
                sk2 = *reinterpret_cast<const us8*>(ksrc + 16);
                sk3 = *reinterpret_cast<const us8*>(ksrc + 24);
                const ushort_t* vsrc = vg + (rowbase + kn + wid * 16) * NQKV + 2 * lane;
#pragma unroll
                for (int j = 0; j < 16; j++)
                    vv2[j] = *reinterpret_cast<const unsigned*>(vsrc + (size_t)j * NQKV);
            }
            __syncthreads();            // buf[cur] ready for all waves

            if (kp0 <= q0 + 31) {       // wave-uniform causal tile skip
                // ---- S^T = K Q^T : col=lane&31 -> q, row crow(r,hi) -> kp ----
                f32x16 s0, s1;
#pragma unroll
                for (int r = 0; r < 16; r++) { s0[r] = 0.f; s1[r] = 0.f; }
                __builtin_amdgcn_s_setprio(1);
#pragma unroll
                for (int ds = 0; ds < 8; ds++) {
                    bf16x8 ka = *reinterpret_cast<const bf16x8*>(
                        &Ks[cur][(l31 * HD + ds * 16 + hi * 8) ^ rswz]);
                    s0 = __builtin_amdgcn_mfma_f32_32x32x16_bf16(ka, qfr[ds], s0, 0, 0, 0);
                }
#pragma unroll
                for (int ds = 0; ds < 8; ds++) {
                    bf16x8 ka = *reinterpret_cast<const bf16x8*>(
                        &Ks[cur][((32 + l31) * HD + ds * 16 + hi * 8) ^ rswz]);
                    s1 = __builtin_amdgcn_mfma_f32_32x32x16_bf16(ka, qfr[ds], s1, 0, 0, 0);
                }
                __builtin_amdgcn_s_setprio(0);
                // ---- causal mask (diagonal tiles only; wave-uniform branch) ----
                if (kp0 + 63 > q0) {
#pragma unroll
                    for (int r = 0; r < 16; r++) {
                        int k0i = kp0 + (r & 3) + 8 * (r >> 2) + 4 * hi;
                        if (k0i > qrow)      s0[r] = -1e30f;
                        if (k0i + 32 > qrow) s1[r] = -1e30f;
                    }
                }
                // ---- row max: 31 in-lane fmax + one lane^32 exchange ----
                float mx = fmaxf(s0[0], s1[0]);
#pragma unroll
                for (int r = 1; r < 16; r++) mx = fmaxf(mx, fmaxf(s0[r], s1[r]));
                mx = fmaxf(mx, __shfl_xor(mx, 32));
                // ---- defer-max rescale (T13, THR=8 in base-2 domain) ----
                if (!__all(mx <= mrun + 8.f)) {
                    float mn = fmaxf(mrun, mx);
                    float al = exp2f(mrun - mn);
#pragma unroll
                    for (int d = 0; d < 4; d++)
#pragma unroll
                        for (int r = 0; r < 16; r++) oacc[d][r] *= al;
                    lsum *= al;
                    mrun = mn;
                }
                // ---- P = 2^(S-m), bf16-pack pairs, row-sum ----
                unsigned pk0[8], pk1[8];
                float ps = 0.f;
#pragma unroll
                for (int w = 0; w < 8; w++) {
                    float a0 = exp2f(s0[2 * w] - mrun), a1 = exp2f(s0[2 * w + 1] - mrun);
                    float b0 = exp2f(s1[2 * w] - mrun), b1 = exp2f(s1[2 * w + 1] - mrun);
                    ps += (a0 + a1) + (b0 + b1);
                    pk0[w] = (unsigned)f2bf(a0) | ((unsigned)f2bf(a1) << 16);
                    pk1[w] = (unsigned)f2bf(b0) | ((unsigned)f2bf(b1) << 16);
                }
                ps += __shfl_xor(ps, 32);
                lsum += ps;
                // ---- O^T += V^T P^T : P-frag per k-slot via lane^32 swap ----
                __builtin_amdgcn_s_setprio(1);
#pragma unroll
                for (int ks = 0; ks < 4; ks++) {
                    const unsigned* pkt = (ks < 2) ? pk0 : pk1;
                    unsigned c00 = pkt[4 * (ks & 1) + 0];
                    unsigned c01 = pkt[4 * (ks & 1) + 1];
                    unsigned c10 = pkt[4 * (ks & 1) + 2];
                    unsigned c11 = pkt[4 * (ks & 1) + 3];
                    unsigned out0 = hi ? c00 : c10;
                    unsigned out1 = hi ? c01 : c11;
                    unsigned rc0 = __shfl_xor(out0, 32);
                    unsigned rc1 = __shfl_xor(out1, 32);
                    u32x4 faw;
                    faw[0] = hi ? rc0 : c00;          // k = 16ks+8hi+{0,1}
                    faw[1] = hi ? rc1 : c01;          // {2,3}
                    faw[2] = hi ? c10 : rc0;          // {4,5}
                    faw[3] = hi ? c11 : rc1;          // {6,7}
                    bf16x8 pa = __builtin_bit_cast(bf16x8, faw);
#pragma unroll
                    for (int dt = 0; dt < 4; dt++) {
                        int doff = dt * 32 + l31;
                        int sr = ((doff >> 3) & 7) << 3;
                        bf16x8 vb = *reinterpret_cast<const bf16x8*>(
                            &Vt[cur][doff * VTS + ((ks * 16 + hi * 8) ^ sr)]);
                        oacc[dt] = __builtin_amdgcn_mfma_f32_32x32x16_bf16(vb, pa, oacc[dt], 0, 0, 0);
                    }
                }
                __builtin_amdgcn_s_setprio(0);
            }
        }

        // ---- epilogue: normalize, pack pairs, store (d = 32dt + crow(r,hi)) ----
        const float rl = 1.f / lsum;
        ushort_t* orow = aout + (rowbase + qrow) * TC + h * HD;
#pragma unroll
        for (int dt = 0; dt < 4; dt++)
#pragma unroll
            for (int rp = 0; rp < 8; rp++) {
                int d = dt * 32 + ((2 * rp) & 3) + 8 * ((2 * rp) >> 2) + 4 * hi;
                unsigned w = (unsigned)f2bf(oacc[dt][2 * rp] * rl)
                           | ((unsigned)f2bf(oacc[dt][2 * rp + 1] * rl) << 16);
                *reinterpret_cast<unsigned*>(orow + d) = w;
            }
    }
}

// ---------------- launch ------------------------------------------------------
extern "C" void kernel_launch(void* const* d_in, const int* in_sizes, int n_in,
                              void* d_out, int out_size, void* d_ws, size_t ws_size,
                              hipStream_t stream) {
    const float* x  = (const float*)d_in[0];
    const float* Wq = (const float*)d_in[1];
    const float* Wk = (const float*)d_in[2];
    const float* Wv = (const float*)d_in[3];
    const float* Wo = (const float*)d_in[4];
    float* out = (float*)d_out;

    ushort_t* x_bf  = (ushort_t*)d_ws;
    ushort_t* wqkv  = x_bf  + (size_t)MTOK * TC;
    ushort_t* wo_bf = wqkv  + (size_t)NQKV * TC;
    ushort_t* qkv   = wo_bf + (size_t)TC * TC;
    ushort_t* attn  = x_bf;                          // alias: x dead after QKV GEMM

    auto nb = [](long n) { long b = (n / 4 + 255) / 256; return (int)(b > 4096 ? 4096 : b); };

    cast_bf16<<<nb((long)MTOK * TC), 256, 0, stream>>>(x, x_bf, (long)MTOK * TC);
    cast_bf16<<<nb((long)TC * TC),   256, 0, stream>>>(Wq, wqkv, (long)TC * TC);
    cast_bf16<<<nb((long)KVDIM * TC),256, 0, stream>>>(Wk, wqkv + (size_t)TC * TC, (long)KVDIM * TC);
    cast_bf16<<<nb((long)KVDIM * TC),256, 0, stream>>>(Wv, wqkv + (size_t)(TC + KVDIM) * TC, (long)KVDIM * TC);
    cast_bf16<<<nb((long)TC * TC),   256, 0, stream>>>(Wo, wo_bf, (long)TC * TC);

    dim3 gq(NQKV / GBN, MTOK / GBM);
    gemm_bt<false, true><<<gq, 256, 0, stream>>>(x_bf, wqkv, nullptr, qkv, MTOK, NQKV, TC);

    attn_kernel<<<dim3(NTB / 2, NH, TB), 256, 0, stream>>>(qkv, attn);

    dim3 go(TC / GBN, MTOK / GBM);
    gemm_bt<true, false><<<go, 256, 0, stream>>>(attn, wo_bf, out, nullptr, MTOK, TC, TC);
}

// Round 5
// 352.693 us; speedup vs baseline: 2.0394x; 1.1524x over previous
//
#include <hip/hip_runtime.h>

#define TB 4
#define TT 2048
#define TC 2048
#define NH 16
#define NKV 4
#define HD 128
#define KVDIM (NKV*HD)        // 512
#define NQKV (TC + 2*KVDIM)   // 3072
#define MTOK (TB*TT)          // 8192

typedef __bf16 bf16x8 __attribute__((ext_vector_type(8)));
typedef float  f32x4  __attribute__((ext_vector_type(4)));
typedef float  f32x16 __attribute__((ext_vector_type(16)));
typedef unsigned short ushort_t;
typedef unsigned short us8 __attribute__((ext_vector_type(8)));
typedef unsigned short us4 __attribute__((ext_vector_type(4)));
typedef unsigned int u32x4 __attribute__((ext_vector_type(4)));

// 1/sqrt(128) * log2(e)  (folded into Q during the QKV GEMM epilogue)
#define QSC 0.12751743f

__device__ __forceinline__ ushort_t f2bf(float f) {
    unsigned u = __builtin_bit_cast(unsigned, f);
    u += 0x7fffu + ((u >> 16) & 1u);
    return (ushort_t)(u >> 16);
}

// async global->LDS, 16B per lane, dest = wave-uniform base + lane*16
__device__ __forceinline__ void gload16(const ushort_t* g, ushort_t* l) {
    __builtin_amdgcn_global_load_lds(
        (const __attribute__((address_space(1))) unsigned int*)g,
        (__attribute__((address_space(3))) unsigned int*)l, 16, 0, 0);
}

// ---------------- cast f32 -> bf16 (vectorized, grid-stride) ----------------
__global__ __launch_bounds__(256) void cast_bf16(const float* __restrict__ in,
                                                 ushort_t* __restrict__ out, long n) {
    long i = (long)blockIdx.x * blockDim.x + threadIdx.x;
    long stride = (long)gridDim.x * blockDim.x;
    for (long e = i * 4; e < n; e += stride * 4) {
        float4 v = *reinterpret_cast<const float4*>(in + e);
        us4 o;
        o[0] = f2bf(v.x); o[1] = f2bf(v.y); o[2] = f2bf(v.z); o[3] = f2bf(v.w);
        *reinterpret_cast<us4*>(out + e) = o;
    }
}

// ---------------- GEMM 256x256, BK=64, 8-phase counted-vmcnt template --------
// C[M][N] = A[M][K](bf16) * Bw[N][K]^T. 512 thr = 8 waves (2M x 4N).
// LDS: 2 buf x (A 256x64 + B 256x64) bf16 = 128 KiB (dynamic).
// Swizzle: 16B-chunk involution pos ^= (row&7); applied on global src (stage)
// and on ds_read addr. Stages barrier-ordered after last read of the region.
#define LBLK 8192   // elements per (buf,mat,half) block: 128 rows x 64 cols

template<bool OUTF32, bool QSCALE>
__global__ __launch_bounds__(512, 2) void gemm256(const ushort_t* __restrict__ A,
                                                  const ushort_t* __restrict__ Bw,
                                                  float* __restrict__ Cf,
                                                  ushort_t* __restrict__ Cb,
                                                  int M, int N, int Kd, int nbn) {
    extern __shared__ ushort_t lds[];
    const int tid = threadIdx.x;
    const int lane = tid & 63, wid = tid >> 6;
    const int wm = wid >> 2, wn = wid & 3;
    const int g = lane >> 4, l16 = lane & 15;

    // XCD-chunked bijective block swizzle (gridDim.x % 8 == 0)
    const int cpx = gridDim.x >> 3;
    const int swz = (blockIdx.x & 7) * cpx + (blockIdx.x >> 3);
    const int bm = swz / nbn, bn = swz % nbn;

    const ushort_t* Ag = A  + (size_t)bm * 256 * Kd;
    const ushort_t* Bg = Bw + (size_t)bn * 256 * Kd;

    // staging geometry: chunk c = j*512 + tid; row = c>>3, src col-chunk = pos^(row&7)
    const int r0 = tid >> 3;
    const int p0 = (tid & 7) ^ (r0 & 7);
    const size_t so0 = (size_t)r0 * Kd + p0 * 8;
    const size_t so1 = so0 + (size_t)64 * Kd;      // j=1: row+64, same pos
    const int ldsw0 = wid * 512;                   // wave's j=0 LDS dest (elements)

    f32x4 acc[8][4] = {};
    bf16x8 aA[4][2], bB[2][2];

    const int NK = Kd >> 6;    // 64-wide K-tiles
    const int NI = Kd >> 7;    // iterations (2 tiles each)

#define STAGE(mat, half, tile) do { if ((tile) < NK) {                                   \
    const ushort_t* sg_ = ((mat) ? Bg : Ag) + (size_t)(half) * 128 * Kd + (size_t)(tile) * 64; \
    ushort_t* lb_ = lds + (((((tile)&1)*2 + (mat))*2 + (half)) * LBLK) + ldsw0;          \
    gload16(sg_ + so0, lb_);                                                             \
    gload16(sg_ + so1, lb_ + 4096);                                                      \
} } while(0)

#define LDA(buf, qm) do {                                                                \
    const ushort_t* Ah_ = lds + (((buf)*2 + 0)*2 + wm) * LBLK;                           \
    _Pragma("unroll") for (int mi_ = 0; mi_ < 4; mi_++) {                                \
        const int r_ = (qm)*64 + mi_*16 + l16;                                           \
        _Pragma("unroll") for (int ks_ = 0; ks_ < 2; ks_++)                              \
            aA[mi_][ks_] = *reinterpret_cast<const bf16x8*>(                             \
                Ah_ + r_*64 + (((ks_*4 + g) ^ (r_ & 7)) * 8));                           \
    }                                                                                    \
} while(0)

#define LDB(buf, qn) do {                                                                \
    const ushort_t* Bh_ = lds + (((buf)*2 + 1)*2 + (wn >> 1)) * LBLK;                    \
    _Pragma("unroll") for (int nj_ = 0; nj_ < 2; nj_++) {                                \
        const int r_ = (wn & 1)*64 + (qn)*32 + nj_*16 + l16;                             \
        _Pragma("unroll") for (int ks_ = 0; ks_ < 2; ks_++)                              \
            bB[nj_][ks_] = *reinterpret_cast<const bf16x8*>(                             \
                Bh_ + r_*64 + (((ks_*4 + g) ^ (r_ & 7)) * 8));                           \
    }                                                                                    \
} while(0)

#define MM(qm, qn) do {                                                                  \
    __builtin_amdgcn_s_setprio(1);                                                       \
    _Pragma("unroll") for (int mi_ = 0; mi_ < 4; mi_++)                                  \
    _Pragma("unroll") for (int nj_ = 0; nj_ < 2; nj_++)                                  \
    _Pragma("unroll") for (int ks_ = 0; ks_ < 2; ks_++)                                  \
        acc[(qm)*4 + mi_][(qn)*2 + nj_] = __builtin_amdgcn_mfma_f32_16x16x32_bf16(       \
            aA[mi_][ks_], bB[nj_][ks_], acc[(qm)*4 + mi_][(qn)*2 + nj_], 0, 0, 0);       \
    __builtin_amdgcn_s_setprio(0);                                                       \
} while(0)

#define PH_MID() do {                                                                    \
    __builtin_amdgcn_s_barrier();                                                        \
    asm volatile("s_waitcnt lgkmcnt(0)" ::: "memory");                                   \
    __builtin_amdgcn_sched_barrier(0);                                                   \
} while(0)

#define PH_END() __builtin_amdgcn_s_barrier()
#define PH_END_VM4() do { asm volatile("s_waitcnt vmcnt(4)" ::: "memory");               \
                          __builtin_amdgcn_s_barrier(); } while(0)
#define PH_END_VM0() do { asm volatile("s_waitcnt vmcnt(0)" ::: "memory");               \
                          __builtin_amdgcn_s_barrier(); } while(0)

    // prologue: tile0 A+B, tile1 A  (12 loads); land tile0, keep tile1-A in flight
    STAGE(0, 0, 0); STAGE(0, 1, 0); STAGE(1, 0, 0); STAGE(1, 1, 0);
    STAGE(0, 0, 1); STAGE(0, 1, 1);
    asm volatile("s_waitcnt vmcnt(4)" ::: "memory");
    __builtin_amdgcn_s_barrier();

    for (int i = 0; i < NI; ++i) {
        const int t0 = 2 * i, t1 = 2 * i + 1;
        const bool last = (i == NI - 1);
        // ph1: tile t0 (buf0) quad(0,0); stage B of t1 (buf1-B free since prev ph8)
        LDA(0, 0); LDB(0, 0);
        STAGE(1, 0, t1); STAGE(1, 1, t1);
        PH_MID(); MM(0, 0); PH_END();
        // ph2: quad(0,1)
        LDB(0, 1);
        PH_MID(); MM(0, 1); PH_END();
        // ph3: quad(1,0)
        LDA(0, 1); LDB(0, 0);
        PH_MID(); MM(1, 0); PH_END();
        // ph4: quad(1,1); stage A of t0+2 (buf0-A free after ph3); vmcnt
        LDB(0, 1);
        STAGE(0, 0, t0 + 2); STAGE(0, 1, t0 + 2);
        PH_MID(); MM(1, 1);
        if (last) PH_END_VM0(); else PH_END_VM4();
        // ph5: tile t1 (buf1) quad(0,0); stage B of t0+2 (buf0-B free after ph4)
        LDA(1, 0); LDB(1, 0);
        STAGE(1, 0, t0 + 2); STAGE(1, 1, t0 + 2);
        PH_MID(); MM(0, 0); PH_END();
        // ph6
        LDB(1, 1);
        PH_MID(); MM(0, 1); PH_END();
        // ph7
        LDA(1, 1); LDB(1, 0);
        PH_MID(); MM(1, 0); PH_END();
        // ph8: stage A of t1+2 (buf1-A free after ph7); vmcnt
        LDB(1, 1);
        STAGE(0, 0, t1 + 2); STAGE(0, 1, t1 + 2);
        PH_MID(); MM(1, 1);
        if (last) PH_END_VM0(); else PH_END_VM4();
    }

    // epilogue: C/D layout col=lane&15, row=(lane>>4)*4+reg
#pragma unroll
    for (int mi = 0; mi < 8; mi++)
#pragma unroll
        for (int nj = 0; nj < 4; nj++) {
            const int rbase = bm * 256 + wm * 128 + mi * 16 + g * 4;
            const int col   = bn * 256 + wn * 64 + nj * 16 + l16;
#pragma unroll
            for (int r = 0; r < 4; r++) {
                float v = acc[mi][nj][r];
                if (QSCALE && col < TC) v *= QSC;
                size_t off = (size_t)(rbase + r) * N + col;
                if (OUTF32) Cf[off] = v;
                else        Cb[off] = f2bf(v);
            }
        }
#undef STAGE
#undef LDA
#undef LDB
#undef MM
#undef PH_MID
#undef PH_END
#undef PH_END_VM4
#undef PH_END_VM0
}

// ---------------- Flash attention (causal, GQA), 32x32 swapped-QK ------------
// grid: (8, NH, B); block processes q-tile pair {15-gx, gx} (uniform 34 K-tiles).
// Double-buffered LDS, loads for t+1 issued before compute of t (T14).
// QK^T: mfma(K,Q) -> S^T (col=q, row=kp). PV: mfma(V^T, P^T) -> O^T (col=q,
// row=d) so per-lane softmax state (q = lane&31) matches accumulator columns.
#define AQB 128
#define AKB 64
#define NTB (TT/AQB)   // 16 q-tiles
#define VTS 72         // Vt row stride (mult of 8 -> 16B rows; banks via XOR swz)

__global__ __launch_bounds__(256, 2) void attn_kernel(const ushort_t* __restrict__ qkv,
                                                      ushort_t* __restrict__ aout) {
    __shared__ alignas(16) ushort_t Ks[2][AKB * HD];   // [kp][d], XOR-swizzled
    __shared__ alignas(16) ushort_t Vt[2][HD * VTS];   // [d][kp], granule-XOR swz

    const int tid  = threadIdx.x;
    const int lane = tid & 63, wid = tid >> 6;
    const int hi   = lane >> 5, l31 = lane & 31;
    const int gx   = blockIdx.x;                 // 0..7
    const int h    = blockIdx.y;
    const int b    = blockIdx.z;
    const int hk   = h >> 2;                     // GQA: kv head = h/4
    const size_t rowbase = (size_t)b * TT;

    const ushort_t* kg = qkv + TC + hk * HD;
    const ushort_t* vg = qkv + TC + KVDIM + hk * HD;
    const int rswz = (l31 & 7) << 3;

    // staging registers (live across the pipeline)
    us8 sk0, sk1, sk2, sk3;
    unsigned vv2[16];
    const int kr = tid >> 2, dc = (tid & 3) * 32;   // K: row, d-col base
    const int vs = ((lane >> 2) & 7) << 3;          // V-write granule swizzle

    for (int phase = 0; phase < 2; ++phase) {
        const int qb = (phase == 0 ? (NTB - 1 - gx) : gx) * AQB;
        const int q0 = qb + wid * 32;
        const int qrow = q0 + l31;

        // Q as B-operand fragments (pre-scaled); col = lane&31 -> q, k-dim = d
        bf16x8 qfr[8];
        {
            const ushort_t* qp = qkv + (rowbase + qrow) * NQKV + h * HD + hi * 8;
#pragma unroll
            for (int s = 0; s < 8; s++)
                qfr[s] = *reinterpret_cast<const bf16x8*>(qp + s * 16);
        }

        f32x16 oacc[4];
#pragma unroll
        for (int d = 0; d < 4; d++)
#pragma unroll
            for (int r = 0; r < 16; r++) oacc[d][r] = 0.f;
        float mrun = -1e30f, lsum = 0.f;

        const int ntiles = qb / AKB + 2;

        // ---- issue loads for tile 0 (into registers) ----
        {
            const ushort_t* ksrc = kg + (rowbase + kr) * NQKV + dc;
            sk0 = *reinterpret_cast<const us8*>(ksrc);
            sk1 = *reinterpret_cast<const us8*>(ksrc + 8);
            sk2 = *reinterpret_cast<const us8*>(ksrc + 16);
            sk3 = *reinterpret_cast<const us8*>(ksrc + 24);
            const ushort_t* vsrc = vg + (rowbase + wid * 16) * NQKV + 2 * lane;
#pragma unroll
            for (int j = 0; j < 16; j++)
                vv2[j] = *reinterpret_cast<const unsigned*>(vsrc + (size_t)j * NQKV);
        }
        if (phase) __syncthreads();     // protect LDS reuse across phases

        for (int t = 0; t < ntiles; ++t) {
            const int kp0 = t * AKB;
            const int cur = t & 1;
            // ---- write staged regs -> LDS buf[cur] ----
            {
                const int kb = kr * HD + dc, ksw = (kr & 7) << 3;
                *reinterpret_cast<us8*>(&Ks[cur][(kb     ) ^ ksw]) = sk0;
                *reinterpret_cast<us8*>(&Ks[cur][(kb +  8) ^ ksw]) = sk1;
                *reinterpret_cast<us8*>(&Ks[cur][(kb + 16) ^ ksw]) = sk2;
                *reinterpret_cast<us8*>(&Ks[cur][(kb + 24) ^ ksw]) = sk3;
                // pack d-pair rows: lo = row 2*lane, hi = row 2*lane+1
                u32x4 pl0, pl1, ph0, ph1;
#pragma unroll
                for (int k = 0; k < 4; k++) {
                    unsigned a = vv2[2 * k], c = vv2[2 * k + 1];
                    pl0[k] = (a & 0xffffu) | (c << 16);
                    ph0[k] = (a >> 16) | (c & 0xffff0000u);
                    unsigned a2 = vv2[8 + 2 * k], c2 = vv2[8 + 2 * k + 1];
                    pl1[k] = (a2 & 0xffffu) | (c2 << 16);
                    ph1[k] = (a2 >> 16) | (c2 & 0xffff0000u);
                }
                ushort_t* r0 = &Vt[cur][(2 * lane) * VTS];
                ushort_t* r1 = &Vt[cur][(2 * lane + 1) * VTS];
                const int o0 = (wid * 16) ^ vs, o1 = (wid * 16 + 8) ^ vs;
                *reinterpret_cast<u32x4*>(r0 + o0) = pl0;
                *reinterpret_cast<u32x4*>(r0 + o1) = pl1;
                *reinterpret_cast<u32x4*>(r1 + o0) = ph0;
                *reinterpret_cast<u32x4*>(r1 + o1) = ph1;
            }
            // ---- issue loads for tile t+1 ----
            if (t + 1 < ntiles) {
                const int kn = (t + 1) * AKB;
                const ushort_t* ksrc = kg + (rowbase + kn + kr) * NQKV + dc;
                sk0 = *reinterpret_cast<const us8*>(ksrc);
                sk1 = *reinterpret_cast<const us8*>(ksrc + 8);
                sk2 = *reinterpret_cast<const us8*>(ksrc + 16);
                sk3 = *reinterpret_cast<const us8*>(ksrc + 24);
                const ushort_t* vsrc = vg + (rowbase + kn + wid * 16) * NQKV + 2 * lane;
#pragma unroll
                for (int j = 0; j < 16; j++)
                    vv2[j] = *reinterpret_cast<const unsigned*>(vsrc + (size_t)j * NQKV);
            }
            __syncthreads();            // buf[cur] ready for all waves

            if (kp0 <= q0 + 31) {       // wave-uniform causal tile skip
                // ---- S^T = K Q^T : col=lane&31 -> q, row crow(r,hi) -> kp ----
                f32x16 s0, s1;
#pragma unroll
                for (int r = 0; r < 16; r++) { s0[r] = 0.f; s1[r] = 0.f; }
                __builtin_amdgcn_s_setprio(1);
#pragma unroll
                for (int ds = 0; ds < 8; ds++) {
                    bf16x8 ka = *reinterpret_cast<const bf16x8*>(
                        &Ks[cur][(l31 * HD + ds * 16 + hi * 8) ^ rswz]);
                    s0 = __builtin_amdgcn_mfma_f32_32x32x16_bf16(ka, qfr[ds], s0, 0, 0, 0);
                }
#pragma unroll
                for (int ds = 0; ds < 8; ds++) {
                    bf16x8 ka = *reinterpret_cast<const bf16x8*>(
                        &Ks[cur][((32 + l31) * HD + ds * 16 + hi * 8) ^ rswz]);
                    s1 = __builtin_amdgcn_mfma_f32_32x32x16_bf16(ka, qfr[ds], s1, 0, 0, 0);
                }
                __builtin_amdgcn_s_setprio(0);
                // ---- causal mask (diagonal tiles only; wave-uniform branch) ----
                if (kp0 + 63 > q0) {
#pragma unroll
                    for (int r = 0; r < 16; r++) {
                        int k0i = kp0 + (r & 3) + 8 * (r >> 2) + 4 * hi;
                        if (k0i > qrow)      s0[r] = -1e30f;
                        if (k0i + 32 > qrow) s1[r] = -1e30f;
                    }
                }
                // ---- row max: 31 in-lane fmax + one lane^32 exchange ----
                float mx = fmaxf(s0[0], s1[0]);
#pragma unroll
                for (int r = 1; r < 16; r++) mx = fmaxf(mx, fmaxf(s0[r], s1[r]));
                mx = fmaxf(mx, __shfl_xor(mx, 32));
                // ---- defer-max rescale (T13, THR=8 in base-2 domain) ----
                if (!__all(mx <= mrun + 8.f)) {
                    float mn = fmaxf(mrun, mx);
                    float al = exp2f(mrun - mn);
#pragma unroll
                    for (int d = 0; d < 4; d++)
#pragma unroll
                        for (int r = 0; r < 16; r++) oacc[d][r] *= al;
                    lsum *= al;
                    mrun = mn;
                }
                // ---- P = 2^(S-m), bf16-pack pairs, row-sum ----
                unsigned pk0[8], pk1[8];
                float ps = 0.f;
#pragma unroll
                for (int w = 0; w < 8; w++) {
                    float a0 = exp2f(s0[2 * w] - mrun), a1 = exp2f(s0[2 * w + 1] - mrun);
                    float b0 = exp2f(s1[2 * w] - mrun), b1 = exp2f(s1[2 * w + 1] - mrun);
                    ps += (a0 + a1) + (b0 + b1);
                    pk0[w] = (unsigned)f2bf(a0) | ((unsigned)f2bf(a1) << 16);
                    pk1[w] = (unsigned)f2bf(b0) | ((unsigned)f2bf(b1) << 16);
                }
                ps += __shfl_xor(ps, 32);
                lsum += ps;
                // ---- O^T += V^T P^T : P-frag per k-slot via lane^32 swap ----
                __builtin_amdgcn_s_setprio(1);
#pragma unroll
                for (int ks = 0; ks < 4; ks++) {
                    const unsigned* pkt = (ks < 2) ? pk0 : pk1;
                    unsigned c00 = pkt[4 * (ks & 1) + 0];
                    unsigned c01 = pkt[4 * (ks & 1) + 1];
                    unsigned c10 = pkt[4 * (ks & 1) + 2];
                    unsigned c11 = pkt[4 * (ks & 1) + 3];
                    unsigned out0 = hi ? c00 : c10;
                    unsigned out1 = hi ? c01 : c11;
                    unsigned rc0 = __shfl_xor(out0, 32);
                    unsigned rc1 = __shfl_xor(out1, 32);
                    u32x4 faw;
                    faw[0] = hi ? rc0 : c00;          // k = 16ks+8hi+{0,1}
                    faw[1] = hi ? rc1 : c01;          // {2,3}
                    faw[2] = hi ? c10 : rc0;          // {4,5}
                    faw[3] = hi ? c11 : rc1;          // {6,7}
                    bf16x8 pa = __builtin_bit_cast(bf16x8, faw);
#pragma unroll
                    for (int dt = 0; dt < 4; dt++) {
                        int doff = dt * 32 + l31;
                        int sr = ((doff >> 3) & 7) << 3;
                        bf16x8 vb = *reinterpret_cast<const bf16x8*>(
                            &Vt[cur][doff * VTS + ((ks * 16 + hi * 8) ^ sr)]);
                        oacc[dt] = __builtin_amdgcn_mfma_f32_32x32x16_bf16(vb, pa, oacc[dt], 0, 0, 0);
                    }
                }
                __builtin_amdgcn_s_setprio(0);
            }
        }

        // ---- epilogue: normalize, pack pairs, store (d = 32dt + crow(r,hi)) ----
        const float rl = 1.f / lsum;
        ushort_t* orow = aout + (rowbase + qrow) * TC + h * HD;
#pragma unroll
        for (int dt = 0; dt < 4; dt++)
#pragma unroll
            for (int rp = 0; rp < 8; rp++) {
                int d = dt * 32 + ((2 * rp) & 3) + 8 * ((2 * rp) >> 2) + 4 * hi;
                unsigned w = (unsigned)f2bf(oacc[dt][2 * rp] * rl)
                           | ((unsigned)f2bf(oacc[dt][2 * rp + 1] * rl) << 16);
                *reinterpret_cast<unsigned*>(orow + d) = w;
            }
    }
}

// ---------------- launch ------------------------------------------------------
extern "C" void kernel_launch(void* const* d_in, const int* in_sizes, int n_in,
                              void* d_out, int out_size, void* d_ws, size_t ws_size,
                              hipStream_t stream) {
    const float* x  = (const float*)d_in[0];
    const float* Wq = (const float*)d_in[1];
    const float* Wk = (const float*)d_in[2];
    const float* Wv = (const float*)d_in[3];
    const float* Wo = (const float*)d_in[4];
    float* out = (float*)d_out;

    ushort_t* x_bf  = (ushort_t*)d_ws;
    ushort_t* wqkv  = x_bf  + (size_t)MTOK * TC;
    ushort_t* wo_bf = wqkv  + (size_t)NQKV * TC;
    ushort_t* qkv   = wo_bf + (size_t)TC * TC;
    ushort_t* attn  = x_bf;                          // alias: x dead after QKV GEMM

    auto nb = [](long n) { long b = (n / 4 + 255) / 256; return (int)(b > 4096 ? 4096 : b); };

    cast_bf16<<<nb((long)MTOK * TC), 256, 0, stream>>>(x, x_bf, (long)MTOK * TC);
    cast_bf16<<<nb((long)TC * TC),   256, 0, stream>>>(Wq, wqkv, (long)TC * TC);
    cast_bf16<<<nb((long)KVDIM * TC),256, 0, stream>>>(Wk, wqkv + (size_t)TC * TC, (long)KVDIM * TC);
    cast_bf16<<<nb((long)KVDIM * TC),256, 0, stream>>>(Wv, wqkv + (size_t)(TC + KVDIM) * TC, (long)KVDIM * TC);
    cast_bf16<<<nb((long)TC * TC),   256, 0, stream>>>(Wo, wo_bf, (long)TC * TC);

    const int GEMM_LDS = 131072;   // 128 KiB dynamic LDS
    hipFuncSetAttribute(reinterpret_cast<const void*>(gemm256<false, true>),
                        hipFuncAttributeMaxDynamicSharedMemorySize, GEMM_LDS);
    hipFuncSetAttribute(reinterpret_cast<const void*>(gemm256<true, false>),
                        hipFuncAttributeMaxDynamicSharedMemorySize, GEMM_LDS);

    // QKV: M=8192, N=3072, K=2048 -> 32x12 = 384 blocks (384 % 8 == 0)
    gemm256<false, true><<<dim3(384), 512, GEMM_LDS, stream>>>(
        x_bf, wqkv, nullptr, qkv, MTOK, NQKV, TC, NQKV / 256);

    attn_kernel<<<dim3(NTB / 2, NH, TB), 256, 0, stream>>>(qkv, attn);

    // out-proj: M=8192, N=2048, K=2048 -> 32x8 = 256 blocks
    gemm256<true, false><<<dim3(256), 512, GEMM_LDS, stream>>>(
        attn, wo_bf, out, nullptr, MTOK, TC, TC, TC / 256);
}